// Round 7
// baseline (520.327 us; speedup 1.0000x reference)
//
#include <hip/hip_runtime.h>
#include <cstdint>

#define BATCH 16
#define NN 131072
#define NCOL 64
#define KOUT 500
#define GG 4
typedef unsigned long long u64;

// Separately-rounded IEEE ops (no FMA contraction) to match numpy/XLA-CPU
// float32 evaluation order in every expression that feeds a discrete decision.
__device__ __forceinline__ float fadd(float a, float b) { return __fadd_rn(a, b); }
__device__ __forceinline__ float fsub(float a, float b) { return __fsub_rn(a, b); }
__device__ __forceinline__ float fmul(float a, float b) { return __fmul_rn(a, b); }

// Box regression exactly as reference apply_regress (dy,dh with scales .1/.2)
__device__ __forceinline__ void regress(float ya, float yb, float dl0, float dl1,
                                        float& ny1, float& ny2) {
    float h  = fsub(yb, ya);
    float cy = fmul(fadd(yb, ya), 0.5f);
    float d0 = fmul(dl0, 0.1f);
    float d1 = fmul(dl1, 0.2f);
    cy = fadd(cy, fmul(d0, h));
    h  = fmul(h, expf(d1));
    ny1 = fsub(cy, fmul(0.5f, h));
    ny2 = fadd(cy, fmul(0.5f, h));
}

// softmax(logits)[1] exactly as jax.nn.softmax (subtract max, exp, normalize)
__device__ __forceinline__ float fg_score(float l0, float l1) {
    float mx = fmaxf(l0, l1);
    float e0 = expf(fsub(l0, mx));
    float e1 = expf(fsub(l1, mx));
    return e1 / fadd(e0, e1);
}

// Full-wave (64-lane) max of a u64 key via DPP (row_shr then row_bcast).
__device__ __forceinline__ u64 wave_max_u64(u64 v) {
#if __has_builtin(__builtin_amdgcn_update_dpp)
    unsigned hi = (unsigned)(v >> 32), lo = (unsigned)(v & 0xffffffffull);
#define DPP_STEP(C)                                                                     \
    {                                                                                   \
        unsigned ohi = (unsigned)__builtin_amdgcn_update_dpp((int)hi, (int)hi, C, 0xf, 0xf, false); \
        unsigned olo = (unsigned)__builtin_amdgcn_update_dpp((int)lo, (int)lo, C, 0xf, 0xf, false); \
        if (ohi > hi || (ohi == hi && olo > lo)) { hi = ohi; lo = olo; }                \
    }
    DPP_STEP(0x111)  // row_shr:1
    DPP_STEP(0x112)  // row_shr:2
    DPP_STEP(0x114)  // row_shr:4
    DPP_STEP(0x118)  // row_shr:8
    DPP_STEP(0x142)  // row_bcast:15
    DPP_STEP(0x143)  // row_bcast:31 -> lane63 has the max
#undef DPP_STEP
    u64 m = ((u64)hi << 32) | lo;
    return __shfl(m, 63);
#else
    for (int o = 32; o; o >>= 1) {
        u64 x = __shfl_xor(v, o);
        if (x > v) v = x;
    }
    return v;
#endif
}

// ---------------------------------------------------------------------------
// K1: gather + softmax + filter + regression + bucket scatter.
// XCD-local mapping: dispatch round-robins blockIdx%8 across the 8 XCDs
// (heuristic), so XCD x works batches {2x, 2x+1} (2x first): the random
// logits/deltas gathers then target a ~2 MB hot set resident in that XCD's
// 4 MB L2, instead of thrashing across the full 33.6 MB (round-6: 185 MB
// DRAM fetch = heavy gather refetch). GG=4 @ 2048 blocks = 8192 waves (100%).
// ---------------------------------------------------------------------------
__global__ __launch_bounds__(256) void k_filter(const float* __restrict__ deltas,
                                                const float* __restrict__ logits,
                                                const float* __restrict__ anchors,
                                                const int* __restrict__ vai,
                                                int* __restrict__ cand_count,
                                                float4* __restrict__ cand,
                                                int cap) {
    int j = blockIdx.x;       // 0..2047
    int x = j & 7;            // XCD (heuristic wgid%8)
    int r = j >> 3;           // 0..255
    int b = 2 * x + (r >> 7); // batch
    int c = r & 127;          // 1024-item chunk within batch
    int base = b * NN + c * 1024;
    int tid = threadIdx.x;
    int g[GG];
#pragma unroll
    for (int k = 0; k < GG; ++k) g[k] = vai[base + tid + (k << 8)];
    float4 an[GG];
#pragma unroll
    for (int k = 0; k < GG; ++k) an[k] = ((const float4*)anchors)[base + tid + (k << 8)];
    float2 lg[GG], dl[GG];
#pragma unroll
    for (int k = 0; k < GG; ++k) {
        size_t p = ((size_t)b * NN + g[k]) * 2;
        lg[k] = *(const float2*)(logits + p);
        dl[k] = *(const float2*)(deltas + p);
    }
#pragma unroll
    for (int k = 0; k < GG; ++k) {
        float s = fg_score(lg[k].x, lg[k].y);
        if (!(s >= 0.7f)) continue;
        int i = (base + tid + (k << 8)) & (NN - 1);  // slot within batch
        float ny1, ny2;
        regress(an[k].x, an[k].z, dl[k].x, dl[k].y, ny1, ny2);
        int col = (int)(an[k].y * 0.0625f);  // x1 = col*16 exactly
        int pos = atomicAdd(&cand_count[b * NCOL + col], 1);
        if (pos < cap)
            cand[(size_t)(b * NCOL + col) * cap + pos] =
                make_float4(s, ny1, ny2, __int_as_float(i));
    }
}

// ---------------------------------------------------------------------------
// K2: per-(batch,col) greedy NMS, one wave per block, statically unrolled
// fused sweep (verified absmax=0 in round 6; unchanged).
// key = score_bits<<32 | (N-1-idx)<<10 | slot : max key == (max score, min
// original idx), matching jnp.argmax first-occurrence ties. key[] slices are
// lane-private -> no barriers in the serial loop (single wave, in-order LDS).
// ---------------------------------------------------------------------------
__global__ __launch_bounds__(64) void k_nms(const int* __restrict__ cand_count,
                                            const float4* __restrict__ cand,
                                            u64* __restrict__ surv,
                                            int* __restrict__ surv_count,
                                            int cap) {
    __shared__ u64 key[1024];
    __shared__ float sy1[1024], sy2[1024];
    int bc = blockIdx.x;
    int lane = threadIdx.x;
    int cnt = cand_count[bc];
    if (cnt > cap) cnt = cap;
    if (cnt > 1024) cnt = 1024;
#pragma unroll
    for (int k = 0; k < 16; ++k) {  // zero-fill pad (single wave: ordered LDS)
        int j = lane + (k << 6);
        key[j] = 0ull; sy1[j] = 0.0f; sy2[j] = 0.0f;
    }
    for (int j = lane; j < cnt; j += 64) {
        float4 c = cand[(size_t)bc * cap + j];
        int idx = __float_as_int(c.w);
        key[j] = ((u64)__float_as_uint(c.x) << 32) |
                 ((unsigned)(NN - 1 - idx) << 10) | (unsigned)j;
        sy1[j] = c.y;
        sy2[j] = c.z;
    }
    u64 best = 0ull;
#pragma unroll
    for (int k = 0; k < 16; ++k) {
        if ((k << 6) < cnt) {
            u64 v = key[lane + (k << 6)];
            if (v > best) best = v;
        }
    }
    best = wave_max_u64(best);
    u64* so = surv + (size_t)bc * KOUT;
    int ns = 0;
    while (best != 0ull) {
        if (lane == 0) so[ns] = best;
        ns++;
        if (ns == KOUT) break;  // >500 per column can never reach global top-500
        int js = (int)(best & 1023ull);
        float ya = sy1[js], yb = sy2[js];
        float a1 = fmul(fsub(yb, ya), 16.0f);  // width exactly 16 -> bit-exact 1D IoU
        u64 nb = 0ull;
#pragma unroll
        for (int k = 0; k < 16; ++k) {
            if ((k << 6) < cnt) {
                int j = lane + (k << 6);
                u64 v = key[j];
                float y1 = sy1[j], y2 = sy2[j];
                float yy1 = fmaxf(ya, y1);
                float yy2 = fminf(yb, y2);
                float inter = fmul(fmaxf(fsub(yy2, yy1), 0.0f), 16.0f);
                float a2 = fmul(fsub(y2, y1), 16.0f);
                // denominator left-to-right: ((a1+a2)-inter)+1e-8, as np does
                float den = fadd(fsub(fadd(a1, a2), inter), 1e-8f);
                float iou = inter / den;
                if (v != 0ull) {
                    if (iou > 0.3f) key[j] = 0ull;  // selected box self-suppresses
                    else if (v > nb) nb = v;        // fused next-argmax
                }
            }
        }
        best = wave_max_u64(nb);
    }
    if (lane == 0) surv_count[bc] = ns;
}

// ---------------------------------------------------------------------------
// K3: merge EIGHT sorted descending unique-key lists -> one top-KOUT list,
// in-block via 3 merge-path levels in LDS (replaces 3 separate launches).
// Capping at KOUT per level is exact (rank>=500 in a subset => rank>=500
// globally). Counts are recomputed from incnt each level (static indexing).
// ---------------------------------------------------------------------------
__device__ __forceinline__ void merge_path(const u64* __restrict__ A, int nA,
                                           const u64* __restrict__ B, int nB,
                                           u64* __restrict__ O, int lane, int nt) {
    int L = nA + nB;
    if (L > KOUT) L = KOUT;
    for (int k = lane; k < L; k += nt) {
        int lo = k - nB; if (lo < 0) lo = 0;
        int hi = k < nA ? k : nA;
        while (lo < hi) {  // find i = #elements taken from A among top-k
            int mid = (lo + hi) >> 1;
            if (A[mid] > B[k - mid - 1]) lo = mid + 1;
            else hi = mid;
        }
        int i = lo, jj = k - lo;
        O[k] = (i < nA && (jj >= nB || A[i] > B[jj])) ? A[i] : B[jj];
    }
}

__global__ __launch_bounds__(256) void k_mtree(const u64* __restrict__ in,
                                               const int* __restrict__ incnt,
                                               u64* __restrict__ outb,
                                               int* __restrict__ outcnt) {
    __shared__ u64 L[8][512];
    __shared__ u64 P[4][512];
    int tid = threadIdx.x;
    int base = blockIdx.x * 8;
    auto nL = [&](int i) { int n = incnt[base + i]; return n > KOUT ? KOUT : n; };
    auto nP = [&](int i) { int n = nL(2 * i) + nL(2 * i + 1); return n > KOUT ? KOUT : n; };
    auto nQ = [&](int i) { int n = nP(2 * i) + nP(2 * i + 1); return n > KOUT ? KOUT : n; };
#pragma unroll
    for (int i = 0; i < 8; ++i) {
        int n = nL(i);
        const u64* p = in + (size_t)(base + i) * KOUT;
        for (int j = tid; j < n; j += 256) L[i][j] = p[j];
    }
    __syncthreads();
    {   // level 1: 4 groups of 64 threads: L[2g],L[2g+1] -> P[g]
        int g = tid >> 6, lane = tid & 63;
        merge_path(L[2 * g], nL(2 * g), L[2 * g + 1], nL(2 * g + 1), P[g], lane, 64);
    }
    __syncthreads();
    {   // level 2: 2 groups of 128: P[2h],P[2h+1] -> L[h] (L dead, reuse)
        int h = tid >> 7, lane = tid & 127;
        merge_path(P[2 * h], nP(2 * h), P[2 * h + 1], nP(2 * h + 1), L[h], lane, 128);
    }
    __syncthreads();
    // level 3: all 256 threads: L[0],L[1] -> global out
    merge_path(L[0], nQ(0), L[1], nQ(1), outb + (size_t)blockIdx.x * KOUT, tid, 256);
    if (tid == 0) {
        int n = nQ(0) + nQ(1);
        outcnt[blockIdx.x] = n > KOUT ? KOUT : n;
    }
}

// ---------------------------------------------------------------------------
// K4: read final merged top-500 list per batch; recompute box/score/logits.
// out = [16,500,5] boxes+mask | [16,500,2] score+mask | [16,500,3] logits+mask
// ---------------------------------------------------------------------------
__global__ void k_out(const u64* __restrict__ finalk,
                      const int* __restrict__ cntF,
                      const float* __restrict__ deltas,
                      const float* __restrict__ logits,
                      const float* __restrict__ anchors,
                      const int* __restrict__ vai,
                      float* __restrict__ out) {
    int t = blockIdx.x * blockDim.x + threadIdx.x;
    if (t >= BATCH * KOUT) return;
    int b = t / KOUT;
    int r = t % KOUT;
    int cnt = cntF[b];
    float y1 = 0, x1 = 0, y2 = 0, x2 = 0, s = 0, l0o = 0, l1o = 0, msk = 0;
    if (r < cnt) {
        u64 key = finalk[(size_t)b * KOUT + r];
        int i = NN - 1 - (int)((key >> 10) & 0x1FFFFull);
        int g = vai[(size_t)b * NN + i];
        size_t lbase = ((size_t)b * NN + g) * 2;
        float l0 = logits[lbase], l1 = logits[lbase + 1];
        s = fg_score(l0, l1);
        const float* an = anchors + ((size_t)b * NN + i) * 4;
        x1 = an[1];
        x2 = an[3];
        regress(an[0], an[2], deltas[lbase], deltas[lbase + 1], y1, y2);
        l0o = l0; l1o = l1; msk = 1.0f;
    }
    float* bo = out + (size_t)t * 5;
    bo[0] = y1; bo[1] = x1; bo[2] = y2; bo[3] = x2; bo[4] = msk;
    float* so = out + BATCH * KOUT * 5 + (size_t)t * 2;
    so[0] = s; so[1] = msk;
    float* lo = out + BATCH * KOUT * 7 + (size_t)t * 3;
    lo[0] = l0o; lo[1] = l1o; lo[2] = msk;
}

// ---------------------------------------------------------------------------
extern "C" void kernel_launch(void* const* d_in, const int* in_sizes, int n_in,
                              void* d_out, int out_size, void* d_ws, size_t ws_size,
                              hipStream_t stream) {
    const float* deltas  = (const float*)d_in[0];
    const float* logits  = (const float*)d_in[1];
    const float* anchors = (const float*)d_in[2];
    const int*   vai     = (const int*)d_in[3];
    float* out = (float*)d_out;

    // workspace layout (cap=1024 is ~23 sigma above the ~561 mean bucket fill;
    // round-3/5/6 passed with cap=1024 => ws_size >= this layout's need)
    int cap = 1024;
    auto need = [&](int c) -> size_t {
        size_t o = (size_t)BATCH * NCOL * 4 * 3;  // cand_count, cntA, cntB
        o = (o + 15) & ~(size_t)15;
        o += (size_t)BATCH * NCOL * c * 16;       // cand (aliased as merge pong)
        o += (size_t)BATCH * NCOL * KOUT * 8;     // surv (merge ping)
        return o;
    };
    while (cap > 256 && need(cap) > ws_size) cap >>= 1;

    char* ws = (char*)d_ws;
    size_t off = 0;
    int* cand_count = (int*)(ws + off); off += (size_t)BATCH * NCOL * 4;
    int* cntA       = (int*)(ws + off); off += (size_t)BATCH * NCOL * 4;  // nms counts; reused for final
    int* cntB       = (int*)(ws + off); off += (size_t)BATCH * NCOL * 4;
    off = (off + 15) & ~(size_t)15;
    float4* cand = (float4*)(ws + off); off += (size_t)BATCH * NCOL * cap * 16;
    u64* surv = (u64*)(ws + off);
    u64* pong = (u64*)cand;  // cand dead after k_nms; >= 2 MB even at cap=256

    hipMemsetAsync(cand_count, 0, (size_t)BATCH * NCOL * 4, stream);
    k_filter<<<2048, 256, 0, stream>>>(
        deltas, logits, anchors, vai, cand_count, cand, cap);
    k_nms<<<BATCH * NCOL, 64, 0, stream>>>(cand_count, cand, surv, cntA, cap);
    // 2-level 8-way merge tree: 1024 -> 128 -> 16 lists
    k_mtree<<<BATCH * 8, 256, 0, stream>>>(surv, cntA, pong, cntB);
    k_mtree<<<BATCH, 256, 0, stream>>>(pong, cntB, surv, cntA);
    k_out<<<(BATCH * KOUT + 255) / 256, 256, 0, stream>>>(
        surv, cntA, deltas, logits, anchors, vai, out);
}

// Round 8
// 336.299 us; speedup vs baseline: 1.5472x; 1.5472x over previous
//
#include <hip/hip_runtime.h>
#include <cstdint>

#define BATCH 16
#define NN 131072
#define NCOL 64
#define KOUT 500
#define GG 8
typedef unsigned long long u64;

// Separately-rounded IEEE ops (no FMA contraction) to match numpy/XLA-CPU
// float32 evaluation order in every expression that feeds a discrete decision.
__device__ __forceinline__ float fadd(float a, float b) { return __fadd_rn(a, b); }
__device__ __forceinline__ float fsub(float a, float b) { return __fsub_rn(a, b); }
__device__ __forceinline__ float fmul(float a, float b) { return __fmul_rn(a, b); }

// Box regression exactly as reference apply_regress (dy,dh with scales .1/.2)
__device__ __forceinline__ void regress(float ya, float yb, float dl0, float dl1,
                                        float& ny1, float& ny2) {
    float h  = fsub(yb, ya);
    float cy = fmul(fadd(yb, ya), 0.5f);
    float d0 = fmul(dl0, 0.1f);
    float d1 = fmul(dl1, 0.2f);
    cy = fadd(cy, fmul(d0, h));
    h  = fmul(h, expf(d1));
    ny1 = fsub(cy, fmul(0.5f, h));
    ny2 = fadd(cy, fmul(0.5f, h));
}

// softmax(logits)[1] exactly as jax.nn.softmax (subtract max, exp, normalize)
__device__ __forceinline__ float fg_score(float l0, float l1) {
    float mx = fmaxf(l0, l1);
    float e0 = expf(fsub(l0, mx));
    float e1 = expf(fsub(l1, mx));
    return e1 / fadd(e0, e1);
}

// Full-wave (64-lane) max of a u64 key via DPP (row_shr then row_bcast).
__device__ __forceinline__ u64 wave_max_u64(u64 v) {
#if __has_builtin(__builtin_amdgcn_update_dpp)
    unsigned hi = (unsigned)(v >> 32), lo = (unsigned)(v & 0xffffffffull);
#define DPP_STEP(C)                                                                     \
    {                                                                                   \
        unsigned ohi = (unsigned)__builtin_amdgcn_update_dpp((int)hi, (int)hi, C, 0xf, 0xf, false); \
        unsigned olo = (unsigned)__builtin_amdgcn_update_dpp((int)lo, (int)lo, C, 0xf, 0xf, false); \
        if (ohi > hi || (ohi == hi && olo > lo)) { hi = ohi; lo = olo; }                \
    }
    DPP_STEP(0x111)  // row_shr:1
    DPP_STEP(0x112)  // row_shr:2
    DPP_STEP(0x114)  // row_shr:4
    DPP_STEP(0x118)  // row_shr:8
    DPP_STEP(0x142)  // row_bcast:15
    DPP_STEP(0x143)  // row_bcast:31 -> lane63 has the max
#undef DPP_STEP
    u64 m = ((u64)hi << 32) | lo;
    return __shfl(m, 63);
#else
    for (int o = 32; o; o >>= 1) {
        u64 x = __shfl_xor(v, o);
        if (x > v) v = x;
    }
    return v;
#endif
}

// ---------------------------------------------------------------------------
// K1: gather + softmax + filter + regression + bucket scatter.
// - One 2048-item chunk of ONE batch per block; XCD-local batch mapping
//   (blockIdx%8 -> XCD heuristic) keeps the random gathers in a ~2 MB
//   L2-resident hot set (round 7: FETCH 185->37 MB).
// - __launch_bounds__(256,4): VGPR cap 128 so ALL loads (4+16+32 dest regs)
//   can be in flight. Round 7's VGPR_Count=24 proved the allocator had
//   serialized them (ILP never materialized; 245us at <3% on every pipe).
// - LDS histogram + one global atomicAdd per (block,col): removes the
//   ~600cy return-atomic from every item's dependent chain; candidate
//   stores become ~9-consecutive-slot bursts per column.
// ---------------------------------------------------------------------------
__global__ __launch_bounds__(256, 4) void k_filter(const float* __restrict__ deltas,
                                                   const float* __restrict__ logits,
                                                   const float* __restrict__ anchors,
                                                   const int* __restrict__ vai,
                                                   int* __restrict__ cand_count,
                                                   float4* __restrict__ cand,
                                                   int cap) {
    __shared__ int lcnt[NCOL];
    __shared__ int gbase[NCOL];
    int j = blockIdx.x;            // 0..1023
    int x = j & 7;                 // XCD (heuristic wgid%8)
    int r = j >> 3;                // 0..127
    int b = 2 * x + (r >> 6);      // batch: XCD x owns batches {2x, 2x+1}
    int c = r & 63;                // 2048-item chunk within batch
    int base = b * NN + c * 2048;
    int tid = threadIdx.x;
    if (tid < NCOL) lcnt[tid] = 0;
    __syncthreads();

    int g[GG];
#pragma unroll
    for (int k = 0; k < GG; ++k) g[k] = vai[base + tid + (k << 8)];
    float4 an[GG];
#pragma unroll
    for (int k = 0; k < GG; ++k) an[k] = ((const float4*)anchors)[base + tid + (k << 8)];
    float2 lg[GG], dl[GG];
#pragma unroll
    for (int k = 0; k < GG; ++k) {
        size_t p = ((size_t)b * NN + g[k]) * 2;
        lg[k] = *(const float2*)(logits + p);
        dl[k] = *(const float2*)(deltas + p);
    }

    float sv[GG], y1v[GG], y2v[GG];
    int colv[GG], lpos[GG];
#pragma unroll
    for (int k = 0; k < GG; ++k) {
        float s = fg_score(lg[k].x, lg[k].y);
        lpos[k] = -1;
        if (s >= 0.7f) {
            regress(an[k].x, an[k].z, dl[k].x, dl[k].y, y1v[k], y2v[k]);
            sv[k] = s;
            int col = (int)(an[k].y * 0.0625f);  // x1 = col*16 exactly
            colv[k] = col;
            lpos[k] = atomicAdd(&lcnt[col], 1);  // LDS atomic (~40cy)
        }
    }
    __syncthreads();
    if (tid < NCOL) gbase[tid] = atomicAdd(&cand_count[b * NCOL + tid], lcnt[tid]);
    __syncthreads();
#pragma unroll
    for (int k = 0; k < GG; ++k) {
        if (lpos[k] >= 0) {
            int col = colv[k];
            int pos = gbase[col] + lpos[k];
            int i = (base + tid + (k << 8)) & (NN - 1);  // slot within batch
            if (pos < cap)
                cand[(size_t)(b * NCOL + col) * cap + pos] =
                    make_float4(sv[k], y1v[k], y2v[k], __int_as_float(i));
        }
    }
}

// ---------------------------------------------------------------------------
// K2: per-(batch,col) greedy NMS, one wave per block, REGISTER-RESIDENT.
// 16 slots/lane (key u64 + y1 + y2 = 64 VGPR) held in registers via fully
// unrolled constant indexing -> the per-selection sweep is pure pipelined
// VALU (rounds 5/6 showed the compiler never pipelined the 16 LDS reads:
// ~16x120cy serial per sweep). LDS (sy1/sy2) only for winner broadcast.
// key = score_bits<<32 | (N-1-idx)<<10 | slot : max key == (max score, min
// original idx), matching jnp.argmax first-occurrence ties; slot is just an
// address tag (idx already unique per batch). Same IEEE ops as absmax=0 ver.
// ---------------------------------------------------------------------------
__global__ __launch_bounds__(64, 1) void k_nms(const int* __restrict__ cand_count,
                                               const float4* __restrict__ cand,
                                               u64* __restrict__ surv,
                                               int* __restrict__ surv_count,
                                               int cap) {
    __shared__ float sy1[1024], sy2[1024];
    int bc = blockIdx.x;
    int lane = threadIdx.x;
    int cnt = cand_count[bc];
    if (cnt > cap) cnt = cap;
    if (cnt > 1024) cnt = 1024;

    u64 kreg[16];
    float y1r[16], y2r[16];
#pragma unroll
    for (int k = 0; k < 16; ++k) {
        int jj = lane + (k << 6);
        u64 kk = 0ull;
        float a = 0.0f, bb = 0.0f;
        if (jj < cnt) {
            float4 cd = cand[(size_t)bc * cap + jj];
            int idx = __float_as_int(cd.w);
            kk = ((u64)__float_as_uint(cd.x) << 32) |
                 ((unsigned)(NN - 1 - idx) << 10) | (unsigned)jj;
            a = cd.y;
            bb = cd.z;
        }
        kreg[k] = kk; y1r[k] = a; y2r[k] = bb;
        sy1[jj] = a; sy2[jj] = bb;   // single wave: in-order LDS, no barrier
    }
    u64 best = 0ull;
#pragma unroll
    for (int k = 0; k < 16; ++k)
        if (kreg[k] > best) best = kreg[k];
    best = wave_max_u64(best);

    u64* so = surv + (size_t)bc * KOUT;
    int ns = 0;
    while (best != 0ull) {
        if (lane == 0) so[ns] = best;
        ns++;
        if (ns == KOUT) break;  // >500 per column can never reach global top-500
        int js = (int)(best & 1023ull);
        float ya = sy1[js], yb = sy2[js];      // broadcast read (same addr)
        float a1 = fmul(fsub(yb, ya), 16.0f);  // width exactly 16 -> bit-exact 1D IoU
        u64 nb = 0ull;
#pragma unroll
        for (int k = 0; k < 16; ++k) {
            if ((k << 6) < cnt) {
                u64 v = kreg[k];
                if (__any(v != 0ull)) {        // uniform skip for dead chunks
                    float yy1 = fmaxf(ya, y1r[k]);
                    float yy2 = fminf(yb, y2r[k]);
                    float inter = fmul(fmaxf(fsub(yy2, yy1), 0.0f), 16.0f);
                    float a2 = fmul(fsub(y2r[k], y1r[k]), 16.0f);
                    // denominator left-to-right: ((a1+a2)-inter)+1e-8, as np
                    float den = fadd(fsub(fadd(a1, a2), inter), 1e-8f);
                    float iou = inter / den;   // exact IEEE div (decision-feeding)
                    if (v != 0ull) {
                        if (iou > 0.3f) kreg[k] = 0ull;  // winner self-suppresses
                        else if (v > nb) nb = v;         // fused next-argmax
                    }
                }
            }
        }
        best = wave_max_u64(nb);
    }
    if (lane == 0) surv_count[bc] = ns;
}

// ---------------------------------------------------------------------------
// K3: merge EIGHT sorted descending unique-key lists -> one top-KOUT list,
// in-block via 3 merge-path levels in LDS. Capping at KOUT per level is
// exact (rank>=500 in a subset => rank>=500 globally).
// ---------------------------------------------------------------------------
__device__ __forceinline__ void merge_path(const u64* __restrict__ A, int nA,
                                           const u64* __restrict__ B, int nB,
                                           u64* __restrict__ O, int lane, int nt) {
    int L = nA + nB;
    if (L > KOUT) L = KOUT;
    for (int k = lane; k < L; k += nt) {
        int lo = k - nB; if (lo < 0) lo = 0;
        int hi = k < nA ? k : nA;
        while (lo < hi) {  // find i = #elements taken from A among top-k
            int mid = (lo + hi) >> 1;
            if (A[mid] > B[k - mid - 1]) lo = mid + 1;
            else hi = mid;
        }
        int i = lo, jj = k - lo;
        O[k] = (i < nA && (jj >= nB || A[i] > B[jj])) ? A[i] : B[jj];
    }
}

__global__ __launch_bounds__(256) void k_mtree(const u64* __restrict__ in,
                                               const int* __restrict__ incnt,
                                               u64* __restrict__ outb,
                                               int* __restrict__ outcnt) {
    __shared__ u64 L[8][512];
    __shared__ u64 P[4][512];
    int tid = threadIdx.x;
    int base = blockIdx.x * 8;
    auto nL = [&](int i) { int n = incnt[base + i]; return n > KOUT ? KOUT : n; };
    auto nP = [&](int i) { int n = nL(2 * i) + nL(2 * i + 1); return n > KOUT ? KOUT : n; };
    auto nQ = [&](int i) { int n = nP(2 * i) + nP(2 * i + 1); return n > KOUT ? KOUT : n; };
#pragma unroll
    for (int i = 0; i < 8; ++i) {
        int n = nL(i);
        const u64* p = in + (size_t)(base + i) * KOUT;
        for (int j = tid; j < n; j += 256) L[i][j] = p[j];
    }
    __syncthreads();
    {   // level 1: 4 groups of 64 threads: L[2g],L[2g+1] -> P[g]
        int g = tid >> 6, lane = tid & 63;
        merge_path(L[2 * g], nL(2 * g), L[2 * g + 1], nL(2 * g + 1), P[g], lane, 64);
    }
    __syncthreads();
    {   // level 2: 2 groups of 128: P[2h],P[2h+1] -> L[h] (L dead, reuse)
        int h = tid >> 7, lane = tid & 127;
        merge_path(P[2 * h], nP(2 * h), P[2 * h + 1], nP(2 * h + 1), L[h], lane, 128);
    }
    __syncthreads();
    // level 3: all 256 threads: L[0],L[1] -> global out
    merge_path(L[0], nQ(0), L[1], nQ(1), outb + (size_t)blockIdx.x * KOUT, tid, 256);
    if (tid == 0) {
        int n = nQ(0) + nQ(1);
        outcnt[blockIdx.x] = n > KOUT ? KOUT : n;
    }
}

// ---------------------------------------------------------------------------
// K4: read final merged top-500 list per batch; recompute box/score/logits.
// out = [16,500,5] boxes+mask | [16,500,2] score+mask | [16,500,3] logits+mask
// ---------------------------------------------------------------------------
__global__ void k_out(const u64* __restrict__ finalk,
                      const int* __restrict__ cntF,
                      const float* __restrict__ deltas,
                      const float* __restrict__ logits,
                      const float* __restrict__ anchors,
                      const int* __restrict__ vai,
                      float* __restrict__ out) {
    int t = blockIdx.x * blockDim.x + threadIdx.x;
    if (t >= BATCH * KOUT) return;
    int b = t / KOUT;
    int r = t % KOUT;
    int cnt = cntF[b];
    float y1 = 0, x1 = 0, y2 = 0, x2 = 0, s = 0, l0o = 0, l1o = 0, msk = 0;
    if (r < cnt) {
        u64 key = finalk[(size_t)b * KOUT + r];
        int i = NN - 1 - (int)((key >> 10) & 0x1FFFFull);
        int g = vai[(size_t)b * NN + i];
        size_t lbase = ((size_t)b * NN + g) * 2;
        float l0 = logits[lbase], l1 = logits[lbase + 1];
        s = fg_score(l0, l1);
        const float* an = anchors + ((size_t)b * NN + i) * 4;
        x1 = an[1];
        x2 = an[3];
        regress(an[0], an[2], deltas[lbase], deltas[lbase + 1], y1, y2);
        l0o = l0; l1o = l1; msk = 1.0f;
    }
    float* bo = out + (size_t)t * 5;
    bo[0] = y1; bo[1] = x1; bo[2] = y2; bo[3] = x2; bo[4] = msk;
    float* so = out + BATCH * KOUT * 5 + (size_t)t * 2;
    so[0] = s; so[1] = msk;
    float* lo = out + BATCH * KOUT * 7 + (size_t)t * 3;
    lo[0] = l0o; lo[1] = l1o; lo[2] = msk;
}

// ---------------------------------------------------------------------------
extern "C" void kernel_launch(void* const* d_in, const int* in_sizes, int n_in,
                              void* d_out, int out_size, void* d_ws, size_t ws_size,
                              hipStream_t stream) {
    const float* deltas  = (const float*)d_in[0];
    const float* logits  = (const float*)d_in[1];
    const float* anchors = (const float*)d_in[2];
    const int*   vai     = (const int*)d_in[3];
    float* out = (float*)d_out;

    // workspace layout (cap=1024 is ~23 sigma above the ~562 mean bucket fill;
    // rounds 3/5/6/7 passed with cap=1024 => ws_size >= this layout's need)
    int cap = 1024;
    auto need = [&](int c) -> size_t {
        size_t o = (size_t)BATCH * NCOL * 4 * 3;  // cand_count, cntA, cntB
        o = (o + 15) & ~(size_t)15;
        o += (size_t)BATCH * NCOL * c * 16;       // cand (aliased as merge pong)
        o += (size_t)BATCH * NCOL * KOUT * 8;     // surv (merge ping)
        return o;
    };
    while (cap > 256 && need(cap) > ws_size) cap >>= 1;

    char* ws = (char*)d_ws;
    size_t off = 0;
    int* cand_count = (int*)(ws + off); off += (size_t)BATCH * NCOL * 4;
    int* cntA       = (int*)(ws + off); off += (size_t)BATCH * NCOL * 4;
    int* cntB       = (int*)(ws + off); off += (size_t)BATCH * NCOL * 4;
    off = (off + 15) & ~(size_t)15;
    float4* cand = (float4*)(ws + off); off += (size_t)BATCH * NCOL * cap * 16;
    u64* surv = (u64*)(ws + off);
    u64* pong = (u64*)cand;  // cand dead after k_nms; >= 2 MB even at cap=256

    hipMemsetAsync(cand_count, 0, (size_t)BATCH * NCOL * 4, stream);
    k_filter<<<1024, 256, 0, stream>>>(
        deltas, logits, anchors, vai, cand_count, cand, cap);
    k_nms<<<BATCH * NCOL, 64, 0, stream>>>(cand_count, cand, surv, cntA, cap);
    // 2-level 8-way merge tree: 1024 -> 128 -> 16 lists
    k_mtree<<<BATCH * 8, 256, 0, stream>>>(surv, cntA, pong, cntB);
    k_mtree<<<BATCH, 256, 0, stream>>>(pong, cntB, surv, cntA);
    k_out<<<(BATCH * KOUT + 255) / 256, 256, 0, stream>>>(
        surv, cntA, deltas, logits, anchors, vai, out);
}

// Round 9
// 334.826 us; speedup vs baseline: 1.5540x; 1.0044x over previous
//
#include <hip/hip_runtime.h>
#include <cstdint>

#define BATCH 16
#define NN 131072
#define NCOL 64
#define KOUT 500
#define GG 8
#define ITERS_A 64
typedef unsigned long long u64;

// Separately-rounded IEEE ops (no FMA contraction) to match numpy/XLA-CPU
// float32 evaluation order in every expression that feeds a discrete decision.
__device__ __forceinline__ float fadd(float a, float b) { return __fadd_rn(a, b); }
__device__ __forceinline__ float fsub(float a, float b) { return __fsub_rn(a, b); }
__device__ __forceinline__ float fmul(float a, float b) { return __fmul_rn(a, b); }

// Box regression exactly as reference apply_regress (dy,dh with scales .1/.2)
__device__ __forceinline__ void regress(float ya, float yb, float dl0, float dl1,
                                        float& ny1, float& ny2) {
    float h  = fsub(yb, ya);
    float cy = fmul(fadd(yb, ya), 0.5f);
    float d0 = fmul(dl0, 0.1f);
    float d1 = fmul(dl1, 0.2f);
    cy = fadd(cy, fmul(d0, h));
    h  = fmul(h, expf(d1));
    ny1 = fsub(cy, fmul(0.5f, h));
    ny2 = fadd(cy, fmul(0.5f, h));
}

// softmax(logits)[1] exactly as jax.nn.softmax (subtract max, exp, normalize)
__device__ __forceinline__ float fg_score(float l0, float l1) {
    float mx = fmaxf(l0, l1);
    float e0 = expf(fsub(l0, mx));
    float e1 = expf(fsub(l1, mx));
    return e1 / fadd(e0, e1);
}

// Full-wave argmax of (key u64) CARRYING the winner's y1,y2 along the DPP
// reduce (4 regs move under one compare) -> no LDS winner-broadcast needed.
__device__ __forceinline__ void wave_argmax_box(u64& key, float& y1, float& y2) {
#if __has_builtin(__builtin_amdgcn_update_dpp)
    unsigned hi = (unsigned)(key >> 32), lo = (unsigned)(key & 0xffffffffull);
    int a = __float_as_int(y1), b = __float_as_int(y2);
#define STEP(C)                                                                         \
    {                                                                                   \
        unsigned ohi = (unsigned)__builtin_amdgcn_update_dpp((int)hi, (int)hi, C, 0xf, 0xf, false); \
        unsigned olo = (unsigned)__builtin_amdgcn_update_dpp((int)lo, (int)lo, C, 0xf, 0xf, false); \
        int oa = __builtin_amdgcn_update_dpp(a, a, C, 0xf, 0xf, false);                 \
        int ob = __builtin_amdgcn_update_dpp(b, b, C, 0xf, 0xf, false);                 \
        if (ohi > hi || (ohi == hi && olo > lo)) { hi = ohi; lo = olo; a = oa; b = ob; } \
    }
    STEP(0x111) STEP(0x112) STEP(0x114) STEP(0x118) STEP(0x142) STEP(0x143)
#undef STEP
    key = __shfl((u64)(((u64)hi << 32) | lo), 63);
    y1  = __shfl(__int_as_float(a), 63);
    y2  = __shfl(__int_as_float(b), 63);
#else
    for (int o = 32; o; o >>= 1) {
        u64 ok = __shfl_xor(key, o);
        float o1 = __shfl_xor(y1, o), o2 = __shfl_xor(y2, o);
        if (ok > key) { key = ok; y1 = o1; y2 = o2; }
    }
#endif
}

// One fused suppression + next-argmax sweep (bit-identical IoU path to the
// absmax=0 round-8 kernel). Winner self-suppresses (IoU==~1 > 0.3).
__device__ __forceinline__ void nms_sweep(u64 (&kreg)[16], const float (&y1r)[16],
                                          const float (&y2r)[16], int cnt,
                                          float ya, float yb,
                                          u64& best, float& by1, float& by2) {
    float a1 = fmul(fsub(yb, ya), 16.0f);  // width exactly 16 -> bit-exact 1D IoU
    u64 pb = 0ull;
    float p1 = 0.0f, p2 = 0.0f;
#pragma unroll
    for (int k = 0; k < 16; ++k) {
        if ((k << 6) < cnt) {
            u64 v = kreg[k];
            if (__any(v != 0ull)) {        // uniform skip for dead chunks
                float yy1 = fmaxf(ya, y1r[k]);
                float yy2 = fminf(yb, y2r[k]);
                float inter = fmul(fmaxf(fsub(yy2, yy1), 0.0f), 16.0f);
                float a2 = fmul(fsub(y2r[k], y1r[k]), 16.0f);
                // denominator left-to-right: ((a1+a2)-inter)+1e-8, as np does
                float den = fadd(fsub(fadd(a1, a2), inter), 1e-8f);
                float iou = inter / den;   // exact IEEE div (decision-feeding)
                if (v != 0ull) {
                    if (iou > 0.3f) kreg[k] = 0ull;
                    else if (v > pb) { pb = v; p1 = y1r[k]; p2 = y2r[k]; }
                }
            }
        }
    }
    best = pb; by1 = p1; by2 = p2;
    wave_argmax_box(best, by1, by2);
}

// ---------------------------------------------------------------------------
// K1: gather + softmax + filter + regression + bucket scatter (round-8 ver).
// ---------------------------------------------------------------------------
__global__ __launch_bounds__(256, 4) void k_filter(const float* __restrict__ deltas,
                                                   const float* __restrict__ logits,
                                                   const float* __restrict__ anchors,
                                                   const int* __restrict__ vai,
                                                   int* __restrict__ cand_count,
                                                   float4* __restrict__ cand,
                                                   int cap) {
    __shared__ int lcnt[NCOL];
    __shared__ int gbase[NCOL];
    int j = blockIdx.x;            // 0..1023
    int x = j & 7;                 // XCD (heuristic wgid%8)
    int r = j >> 3;                // 0..127
    int b = 2 * x + (r >> 6);      // batch: XCD x owns batches {2x, 2x+1}
    int c = r & 63;                // 2048-item chunk within batch
    int base = b * NN + c * 2048;
    int tid = threadIdx.x;
    if (tid < NCOL) lcnt[tid] = 0;
    __syncthreads();

    int g[GG];
#pragma unroll
    for (int k = 0; k < GG; ++k) g[k] = vai[base + tid + (k << 8)];
    float4 an[GG];
#pragma unroll
    for (int k = 0; k < GG; ++k) an[k] = ((const float4*)anchors)[base + tid + (k << 8)];
    float2 lg[GG], dl[GG];
#pragma unroll
    for (int k = 0; k < GG; ++k) {
        size_t p = ((size_t)b * NN + g[k]) * 2;
        lg[k] = *(const float2*)(logits + p);
        dl[k] = *(const float2*)(deltas + p);
    }

    float sv[GG], y1v[GG], y2v[GG];
    int colv[GG], lpos[GG];
#pragma unroll
    for (int k = 0; k < GG; ++k) {
        float s = fg_score(lg[k].x, lg[k].y);
        lpos[k] = -1;
        if (s >= 0.7f) {
            regress(an[k].x, an[k].z, dl[k].x, dl[k].y, y1v[k], y2v[k]);
            sv[k] = s;
            int col = (int)(an[k].y * 0.0625f);  // x1 = col*16 exactly
            colv[k] = col;
            lpos[k] = atomicAdd(&lcnt[col], 1);
        }
    }
    __syncthreads();
    if (tid < NCOL) gbase[tid] = atomicAdd(&cand_count[b * NCOL + tid], lcnt[tid]);
    __syncthreads();
#pragma unroll
    for (int k = 0; k < GG; ++k) {
        if (lpos[k] >= 0) {
            int col = colv[k];
            int pos = gbase[col] + lpos[k];
            int i = (base + tid + (k << 8)) & (NN - 1);
            if (pos < cap)
                cand[(size_t)(b * NCOL + col) * cap + pos] =
                    make_float4(sv[k], y1v[k], y2v[k], __int_as_float(i));
        }
    }
}

// ---------------------------------------------------------------------------
// K2a: per-(batch,col) greedy NMS prefix, register-resident, max `iters`
// selections. Saves alive mask (ballots) + next-best key for exact resume.
// With iters=KOUT and aliveB==nullptr this is exactly the round-8 kernel.
// ---------------------------------------------------------------------------
__global__ __launch_bounds__(64, 1) void k_nmsA(const int* __restrict__ cand_count,
                                                const float4* __restrict__ cand,
                                                u64* __restrict__ surv,
                                                int* __restrict__ surv_count,
                                                u64* __restrict__ aliveB,
                                                u64* __restrict__ nextb,
                                                int cap, int iters) {
    int bc = blockIdx.x;
    int lane = threadIdx.x;
    int cnt = cand_count[bc];
    if (cnt > cap) cnt = cap;
    if (cnt > 1024) cnt = 1024;

    u64 kreg[16];
    float y1r[16], y2r[16];
#pragma unroll
    for (int k = 0; k < 16; ++k) {
        int jj = lane + (k << 6);
        u64 kk = 0ull; float a = 0.0f, bb = 0.0f;
        if (jj < cnt) {
            float4 cd = cand[(size_t)bc * cap + jj];
            int idx = __float_as_int(cd.w);
            kk = ((u64)__float_as_uint(cd.x) << 32) |
                 ((unsigned)(NN - 1 - idx) << 10) | (unsigned)jj;
            a = cd.y; bb = cd.z;
        }
        kreg[k] = kk; y1r[k] = a; y2r[k] = bb;
    }
    u64 best = 0ull; float ya = 0.0f, yb = 0.0f;
#pragma unroll
    for (int k = 0; k < 16; ++k)
        if (kreg[k] > best) { best = kreg[k]; ya = y1r[k]; yb = y2r[k]; }
    wave_argmax_box(best, ya, yb);

    u64* so = surv + (size_t)bc * KOUT;
    int ns = 0;
    while (best != 0ull) {
        if (lane == 0) so[ns] = best;
        ns++;
        if (ns >= KOUT) break;
        nms_sweep(kreg, y1r, y2r, cnt, ya, yb, best, ya, yb);
        if (ns >= iters) break;   // stop AFTER sweep: winner is dead in state
    }
    if (lane == 0) surv_count[bc] = ns;
    if (aliveB != nullptr) {
        if (lane == 0) nextb[bc] = best;
#pragma unroll
        for (int k = 0; k < 16; ++k) {
            u64 m = __ballot(kreg[k] != 0ull);
            if (lane == 0) aliveB[(size_t)bc * 16 + k] = m;
        }
    }
}

// ---------------------------------------------------------------------------
// K2b: resume greedy NMS while next-best key >= L (batch's phase-A 500th
// merged key). L <= true 500th selected key, and column selections descend,
// so truncated tails can never enter the global top-500 => exact.
// ---------------------------------------------------------------------------
__global__ __launch_bounds__(64, 1) void k_nmsB(const int* __restrict__ cand_count,
                                                const float4* __restrict__ cand,
                                                const u64* __restrict__ aliveB,
                                                const u64* __restrict__ nextb,
                                                u64* __restrict__ surv,
                                                int* __restrict__ surv_count,
                                                const u64* __restrict__ finalk,
                                                const int* __restrict__ cntF,
                                                int cap) {
    int bc = blockIdx.x;
    int lane = threadIdx.x;
    int ns = surv_count[bc];
    if (ns >= KOUT) return;
    int b = bc >> 6;
    u64 L = (cntF[b] >= KOUT) ? finalk[(size_t)b * KOUT + (KOUT - 1)] : 0ull;
    u64 nb0 = nextb[bc];
    if (nb0 == 0ull || nb0 < L) return;   // exhausted or below bound (~99% exit)

    int cnt = cand_count[bc];
    if (cnt > cap) cnt = cap;
    if (cnt > 1024) cnt = 1024;
    u64 kreg[16];
    float y1r[16], y2r[16];
#pragma unroll
    for (int k = 0; k < 16; ++k) {
        int jj = lane + (k << 6);
        u64 kk = 0ull; float a = 0.0f, bb = 0.0f;
        if (jj < cnt) {
            float4 cd = cand[(size_t)bc * cap + jj];
            int idx = __float_as_int(cd.w);
            kk = ((u64)__float_as_uint(cd.x) << 32) |
                 ((unsigned)(NN - 1 - idx) << 10) | (unsigned)jj;
            a = cd.y; bb = cd.z;
        }
        if (!((aliveB[(size_t)bc * 16 + k] >> lane) & 1ull)) kk = 0ull;
        kreg[k] = kk; y1r[k] = a; y2r[k] = bb;
    }
    u64 best = 0ull; float ya = 0.0f, yb = 0.0f;
#pragma unroll
    for (int k = 0; k < 16; ++k)
        if (kreg[k] > best) { best = kreg[k]; ya = y1r[k]; yb = y2r[k]; }
    wave_argmax_box(best, ya, yb);

    u64* so = surv + (size_t)bc * KOUT;
    while (best != 0ull && best >= L) {
        if (lane == 0) so[ns] = best;
        ns++;
        if (ns >= KOUT) break;
        nms_sweep(kreg, y1r, y2r, cnt, ya, yb, best, ya, yb);
    }
    if (lane == 0) surv_count[bc] = ns;
}

// ---------------------------------------------------------------------------
// K3: merge EIGHT sorted descending unique-key lists -> one top-KOUT list
// (3 in-block merge-path levels; per-level KOUT cap is exact).
// ---------------------------------------------------------------------------
__device__ __forceinline__ void merge_path(const u64* __restrict__ A, int nA,
                                           const u64* __restrict__ B, int nB,
                                           u64* __restrict__ O, int lane, int nt) {
    int L = nA + nB;
    if (L > KOUT) L = KOUT;
    for (int k = lane; k < L; k += nt) {
        int lo = k - nB; if (lo < 0) lo = 0;
        int hi = k < nA ? k : nA;
        while (lo < hi) {
            int mid = (lo + hi) >> 1;
            if (A[mid] > B[k - mid - 1]) lo = mid + 1;
            else hi = mid;
        }
        int i = lo, jj = k - lo;
        O[k] = (i < nA && (jj >= nB || A[i] > B[jj])) ? A[i] : B[jj];
    }
}

__global__ __launch_bounds__(256) void k_mtree(const u64* __restrict__ in,
                                               const int* __restrict__ incnt,
                                               u64* __restrict__ outb,
                                               int* __restrict__ outcnt) {
    __shared__ u64 L[8][512];
    __shared__ u64 P[4][512];
    int tid = threadIdx.x;
    int base = blockIdx.x * 8;
    auto nL = [&](int i) { int n = incnt[base + i]; return n > KOUT ? KOUT : n; };
    auto nP = [&](int i) { int n = nL(2 * i) + nL(2 * i + 1); return n > KOUT ? KOUT : n; };
    auto nQ = [&](int i) { int n = nP(2 * i) + nP(2 * i + 1); return n > KOUT ? KOUT : n; };
#pragma unroll
    for (int i = 0; i < 8; ++i) {
        int n = nL(i);
        const u64* p = in + (size_t)(base + i) * KOUT;
        for (int j = tid; j < n; j += 256) L[i][j] = p[j];
    }
    __syncthreads();
    {
        int g = tid >> 6, lane = tid & 63;
        merge_path(L[2 * g], nL(2 * g), L[2 * g + 1], nL(2 * g + 1), P[g], lane, 64);
    }
    __syncthreads();
    {
        int h = tid >> 7, lane = tid & 127;
        merge_path(P[2 * h], nP(2 * h), P[2 * h + 1], nP(2 * h + 1), L[h], lane, 128);
    }
    __syncthreads();
    merge_path(L[0], nQ(0), L[1], nQ(1), outb + (size_t)blockIdx.x * KOUT, tid, 256);
    if (tid == 0) {
        int n = nQ(0) + nQ(1);
        outcnt[blockIdx.x] = n > KOUT ? KOUT : n;
    }
}

// ---------------------------------------------------------------------------
// K4: read final per-batch top-500 list; recompute box/score/logits.
// out = [16,500,5] boxes+mask | [16,500,2] score+mask | [16,500,3] logits+mask
// ---------------------------------------------------------------------------
__global__ void k_out(const u64* __restrict__ finalk,
                      const int* __restrict__ cntF,
                      const float* __restrict__ deltas,
                      const float* __restrict__ logits,
                      const float* __restrict__ anchors,
                      const int* __restrict__ vai,
                      float* __restrict__ out) {
    int t = blockIdx.x * blockDim.x + threadIdx.x;
    if (t >= BATCH * KOUT) return;
    int b = t / KOUT;
    int r = t % KOUT;
    int cnt = cntF[b];
    float y1 = 0, x1 = 0, y2 = 0, x2 = 0, s = 0, l0o = 0, l1o = 0, msk = 0;
    if (r < cnt) {
        u64 key = finalk[(size_t)b * KOUT + r];
        int i = NN - 1 - (int)((key >> 10) & 0x1FFFFull);
        int g = vai[(size_t)b * NN + i];
        size_t lbase = ((size_t)b * NN + g) * 2;
        float l0 = logits[lbase], l1 = logits[lbase + 1];
        s = fg_score(l0, l1);
        const float* an = anchors + ((size_t)b * NN + i) * 4;
        x1 = an[1];
        x2 = an[3];
        regress(an[0], an[2], deltas[lbase], deltas[lbase + 1], y1, y2);
        l0o = l0; l1o = l1; msk = 1.0f;
    }
    float* bo = out + (size_t)t * 5;
    bo[0] = y1; bo[1] = x1; bo[2] = y2; bo[3] = x2; bo[4] = msk;
    float* so = out + BATCH * KOUT * 5 + (size_t)t * 2;
    so[0] = s; so[1] = msk;
    float* lo = out + BATCH * KOUT * 7 + (size_t)t * 3;
    lo[0] = l0o; lo[1] = l1o; lo[2] = msk;
}

// ---------------------------------------------------------------------------
extern "C" void kernel_launch(void* const* d_in, const int* in_sizes, int n_in,
                              void* d_out, int out_size, void* d_ws, size_t ws_size,
                              hipStream_t stream) {
    const float* deltas  = (const float*)d_in[0];
    const float* logits  = (const float*)d_in[1];
    const float* anchors = (const float*)d_in[2];
    const int*   vai     = (const int*)d_in[3];
    float* out = (float*)d_out;

    char* ws = (char*)d_ws;
    int cap = 1024;

    // --- full (two-phase) layout ---
    size_t off = 0;
    auto alloc = [&](size_t bytes) { void* p = ws + off; off += (bytes + 15) & ~(size_t)15; return p; };
    int* cand_count = (int*)alloc(BATCH * NCOL * 4);
    int* cntA       = (int*)alloc(BATCH * NCOL * 4);
    int* cntM       = (int*)alloc(512 * 4);
    int* cntF       = (int*)alloc(64);
    u64* nextb      = (u64*)alloc(BATCH * NCOL * 8);
    u64* alive      = (u64*)alloc((size_t)BATCH * NCOL * 16 * 8);
    float4* cand    = (float4*)alloc((size_t)BATCH * NCOL * cap * 16);
    u64* surv       = (u64*)alloc((size_t)BATCH * NCOL * KOUT * 8);
    u64* pong       = (u64*)alloc((size_t)BATCH * 8 * KOUT * 8);
    u64* finalb     = (u64*)alloc((size_t)BATCH * KOUT * 8);
    bool full = (off <= ws_size);

    if (full) {
        hipMemsetAsync(cand_count, 0, (size_t)BATCH * NCOL * 4, stream);
        k_filter<<<1024, 256, 0, stream>>>(deltas, logits, anchors, vai,
                                           cand_count, cand, cap);
        k_nmsA<<<BATCH * NCOL, 64, 0, stream>>>(cand_count, cand, surv, cntA,
                                                alive, nextb, cap, ITERS_A);
        k_mtree<<<BATCH * 8, 256, 0, stream>>>(surv, cntA, pong, cntM);
        k_mtree<<<BATCH, 256, 0, stream>>>(pong, cntM, finalb, cntF);
        k_nmsB<<<BATCH * NCOL, 64, 0, stream>>>(cand_count, cand, alive, nextb,
                                                surv, cntA, finalb, cntF, cap);
        k_mtree<<<BATCH * 8, 256, 0, stream>>>(surv, cntA, pong, cntM);
        k_mtree<<<BATCH, 256, 0, stream>>>(pong, cntM, finalb, cntF);
        k_out<<<(BATCH * KOUT + 255) / 256, 256, 0, stream>>>(
            finalb, cntF, deltas, logits, anchors, vai, out);
    } else {
        // --- fallback: exact round-8 single-phase pipeline (pong aliases cand) ---
        auto need = [&](int c) -> size_t {
            size_t o = (size_t)BATCH * NCOL * 4 * 2 + 512 * 4;
            o = (o + 15) & ~(size_t)15;
            o += (size_t)BATCH * NCOL * c * 16;
            o += (size_t)BATCH * NCOL * KOUT * 8;
            return o;
        };
        while (cap > 256 && need(cap) > ws_size) cap >>= 1;
        off = 0;
        cand_count = (int*)alloc(BATCH * NCOL * 4);
        cntA       = (int*)alloc(BATCH * NCOL * 4);
        cntM       = (int*)alloc(512 * 4);
        cand       = (float4*)alloc((size_t)BATCH * NCOL * cap * 16);
        surv       = (u64*)alloc((size_t)BATCH * NCOL * KOUT * 8);
        pong       = (u64*)cand;  // cand dead after k_nmsA in this path

        hipMemsetAsync(cand_count, 0, (size_t)BATCH * NCOL * 4, stream);
        k_filter<<<1024, 256, 0, stream>>>(deltas, logits, anchors, vai,
                                           cand_count, cand, cap);
        k_nmsA<<<BATCH * NCOL, 64, 0, stream>>>(cand_count, cand, surv, cntA,
                                                (u64*)nullptr, (u64*)nullptr, cap, KOUT);
        k_mtree<<<BATCH * 8, 256, 0, stream>>>(surv, cntA, pong, cntM);
        k_mtree<<<BATCH, 256, 0, stream>>>(pong, cntM, surv, cntA);
        k_out<<<(BATCH * KOUT + 255) / 256, 256, 0, stream>>>(
            surv, cntA, deltas, logits, anchors, vai, out);
    }
}